// Round 9
// baseline (258.043 us; speedup 1.0000x reference)
//
#include <hip/hip_runtime.h>
#include <math.h>

// LSMLoss: triplet cosine margin loss.
//   loss = mean_e[ softplus(-(cos(a,p)-K)/T) + softplus((cos(a,n)-K)/T) ]
// K=0.5, T=0.1, eps=1e-8 (torch CosineSimilarity norm clamp).
// feats: [500000, 64] fp32; tplts: [3, N] int32 (anchor/pos/neg row ids).
//
// R9 = R8 with ONE diagnostic change: phase 1 repeats its full row sweep
// TWICE (idempotent; identical stores). Purpose: a single ~2x-p1 dispatch
// (~100 us) exceeds the 74 us fillBuffer floor and surfaces in rocprof
// top-5 with counters (p1 has never been directly observed; two p1
// optimization theories in a row under-delivered). FETCH_SIZE / VALUBusy /
// hbm_gbps on that row discriminate HBM-stream vs VALU-bound vs latency.
// Remove the rep loop next round once attributed.

#define LSM_K 0.5f
#define LSM_INV_T 10.0f
#define LSM_EPS 1e-8f
#define N_FEAT 64
#define FP8_SCALE 32.0f
#define FP8_INV_SCALE2 (1.0f / (FP8_SCALE * FP8_SCALE))

typedef float f32x2 __attribute__((ext_vector_type(2)));
typedef float f32x4 __attribute__((ext_vector_type(4)));

__device__ __forceinline__ float softplus_f(float x) {
    // matches jax.nn.softplus: max(x,0) + log1p(exp(-|x|))
    return fmaxf(x, 0.0f) + log1pf(expf(-fabsf(x)));
}

// ---------------- Phase 1: fp32 -> normalized fp8 table (+ zero out) ----
// 16 lanes per row; 2 consecutive rows per group per iteration.
// DIAGNOSTIC: rep loop runs the sweep twice.
__global__ __launch_bounds__(256) void normalize_fp8_kernel(
    const float*  __restrict__ feats,
    unsigned int* __restrict__ nfeats,
    float*        __restrict__ out,
    int n_rows)
{
    if (blockIdx.x == 0 && threadIdx.x == 0) *out = 0.0f;  // runs before phase 2

    const int gl = threadIdx.x & 15;
    const int g  = (int)((blockIdx.x * blockDim.x + threadIdx.x) >> 4);
    const int ng = (int)((gridDim.x * blockDim.x) >> 4);
    const int n_pair = n_rows >> 1;

    for (int rep = 0; rep < 2; ++rep) {   // DIAGNOSTIC x2 — remove after R9
        for (int pr = g; pr < n_pair; pr += ng) {
            const int r0 = pr << 1;
            const f32x4 v0 = __builtin_nontemporal_load(
                (const f32x4*)(feats + (size_t)r0 * N_FEAT) + gl);
            const f32x4 v1 = __builtin_nontemporal_load(
                (const f32x4*)(feats + (size_t)(r0 + 1) * N_FEAT) + gl);

            float s0 = v0.x*v0.x + v0.y*v0.y + v0.z*v0.z + v0.w*v0.w;
            float s1 = v1.x*v1.x + v1.y*v1.y + v1.z*v1.z + v1.w*v1.w;
            #pragma unroll
            for (int m = 1; m < 16; m <<= 1) {
                s0 += __shfl_xor(s0, m, 64);
                s1 += __shfl_xor(s1, m, 64);
            }
            const float sc0 = FP8_SCALE / fmaxf(sqrtf(s0), LSM_EPS);
            const float sc1 = FP8_SCALE / fmaxf(sqrtf(s1), LSM_EPS);

            int pk0 = __builtin_amdgcn_cvt_pk_fp8_f32(v0.x * sc0, v0.y * sc0, 0, false);
            pk0     = __builtin_amdgcn_cvt_pk_fp8_f32(v0.z * sc0, v0.w * sc0, pk0, true);
            int pk1 = __builtin_amdgcn_cvt_pk_fp8_f32(v1.x * sc1, v1.y * sc1, 0, false);
            pk1     = __builtin_amdgcn_cvt_pk_fp8_f32(v1.z * sc1, v1.w * sc1, pk1, true);

            nfeats[(size_t)r0 * 16 + gl]       = (unsigned int)pk0;
            nfeats[(size_t)(r0 + 1) * 16 + gl] = (unsigned int)pk1;
        }
    }

    // tail row if n_rows is odd (not the case at 500k, but stay correct)
    if ((n_rows & 1) && g == 0) {
        const int r = n_rows - 1;
        const f32x4 v = *((const f32x4*)(feats + (size_t)r * N_FEAT) + gl);
        float s = v.x*v.x + v.y*v.y + v.z*v.z + v.w*v.w;
        #pragma unroll
        for (int m = 1; m < 16; m <<= 1)
            s += __shfl_xor(s, m, 64);
        const float sc = FP8_SCALE / fmaxf(sqrtf(s), LSM_EPS);
        int pk = __builtin_amdgcn_cvt_pk_fp8_f32(v.x * sc, v.y * sc, 0, false);
        pk     = __builtin_amdgcn_cvt_pk_fp8_f32(v.z * sc, v.w * sc, pk, true);
        nfeats[(size_t)r * 16 + gl] = (unsigned int)pk;
    }
}

// lane-partial dots of one triplet's 16 B chunks: returns {s_ap, s_an}
__device__ __forceinline__ f32x2 dots3_fp8(const uint4 a, const uint4 p, const uint4 q) {
    const unsigned int aw[4] = {a.x, a.y, a.z, a.w};
    const unsigned int pw[4] = {p.x, p.y, p.z, p.w};
    const unsigned int qw[4] = {q.x, q.y, q.z, q.w};
    f32x2 accp = {0.0f, 0.0f};
    f32x2 accn = {0.0f, 0.0f};
    #pragma unroll
    for (int d = 0; d < 4; ++d) {
        const f32x2 alo = __builtin_amdgcn_cvt_pk_f32_fp8(aw[d], false);
        const f32x2 ahi = __builtin_amdgcn_cvt_pk_f32_fp8(aw[d], true);
        const f32x2 plo = __builtin_amdgcn_cvt_pk_f32_fp8(pw[d], false);
        const f32x2 phi = __builtin_amdgcn_cvt_pk_f32_fp8(pw[d], true);
        const f32x2 qlo = __builtin_amdgcn_cvt_pk_f32_fp8(qw[d], false);
        const f32x2 qhi = __builtin_amdgcn_cvt_pk_f32_fp8(qw[d], true);
        accp += alo * plo;   // v_pk_fma_f32
        accp += ahi * phi;
        accn += alo * qlo;
        accn += ahi * qhi;
    }
    f32x2 r;
    r.x = (accp.x + accp.y) * FP8_INV_SCALE2;
    r.y = (accn.x + accn.y) * FP8_INV_SCALE2;
    return r;
}

// ---------------- Phase 2: batched gather (4 triplets/group/iter) -------
// Unchanged from R5.
__global__ __launch_bounds__(256) void lsm_loss_fp8_kernel(
    const uint4* __restrict__ nfeats4,   // 4 x uint4 per row
    const int*   __restrict__ tplts,
    float*       __restrict__ out,
    int n_trip)                           // must be % 4 == 0 (launcher guards)
{
    const int lane = threadIdx.x & 63;
    const int gl   = threadIdx.x & 3;
    const int g        = (int)((blockIdx.x * blockDim.x + threadIdx.x) >> 2);
    const int n_groups = (int)((gridDim.x * blockDim.x) >> 2);

    const int* __restrict__ A  = tplts;
    const int* __restrict__ P  = tplts + n_trip;
    const int* __restrict__ Ng = tplts + 2 * n_trip;

    float local = 0.0f;
    const int n_batch = n_trip >> 2;

    for (int b = g; b < n_batch; b += n_groups) {
        const int t0 = b << 2;
        const int4 ia = *(const int4*)(A  + t0);
        const int4 ip = *(const int4*)(P  + t0);
        const int4 iq = *(const int4*)(Ng + t0);

        const uint4 a0 = nfeats4[(size_t)ia.x * 4 + gl];
        const uint4 a1 = nfeats4[(size_t)ia.y * 4 + gl];
        const uint4 a2 = nfeats4[(size_t)ia.z * 4 + gl];
        const uint4 a3 = nfeats4[(size_t)ia.w * 4 + gl];
        const uint4 p0 = nfeats4[(size_t)ip.x * 4 + gl];
        const uint4 p1 = nfeats4[(size_t)ip.y * 4 + gl];
        const uint4 p2 = nfeats4[(size_t)ip.z * 4 + gl];
        const uint4 p3 = nfeats4[(size_t)ip.w * 4 + gl];
        const uint4 q0 = nfeats4[(size_t)iq.x * 4 + gl];
        const uint4 q1 = nfeats4[(size_t)iq.y * 4 + gl];
        const uint4 q2 = nfeats4[(size_t)iq.z * 4 + gl];
        const uint4 q3 = nfeats4[(size_t)iq.w * 4 + gl];

        f32x2 s0 = dots3_fp8(a0, p0, q0);
        f32x2 s1 = dots3_fp8(a1, p1, q1);
        f32x2 s2 = dots3_fp8(a2, p2, q2);
        f32x2 s3 = dots3_fp8(a3, p3, q3);

        #pragma unroll
        for (int m = 1; m < 4; m <<= 1) {
            s0.x += __shfl_xor(s0.x, m, 64);  s0.y += __shfl_xor(s0.y, m, 64);
            s1.x += __shfl_xor(s1.x, m, 64);  s1.y += __shfl_xor(s1.y, m, 64);
            s2.x += __shfl_xor(s2.x, m, 64);  s2.y += __shfl_xor(s2.y, m, 64);
            s3.x += __shfl_xor(s3.x, m, 64);  s3.y += __shfl_xor(s3.y, m, 64);
        }

        float my_ap = s0.x, my_an = s0.y;
        if (gl == 1) { my_ap = s1.x; my_an = s1.y; }
        if (gl == 2) { my_ap = s2.x; my_an = s2.y; }
        if (gl == 3) { my_ap = s3.x; my_an = s3.y; }

        local += softplus_f(-(my_ap - LSM_K) * LSM_INV_T)
               + softplus_f( (my_an - LSM_K) * LSM_INV_T);
    }

    float v = local;
    #pragma unroll
    for (int m = 1; m < 64; m <<= 1)
        v += __shfl_xor(v, m, 64);

    __shared__ float wave_sums[4];
    const int wave_id = threadIdx.x >> 6;
    if (lane == 0) wave_sums[wave_id] = v;
    __syncthreads();

    if (threadIdx.x == 0) {
        float s = wave_sums[0] + wave_sums[1] + wave_sums[2] + wave_sums[3];
        atomicAdd(out, s * (1.0f / (float)n_trip));
    }
}

// ---------------- Fallback (R2, fp32 direct) ----------------------------
__global__ __launch_bounds__(256) void lsm_loss_f32_kernel(
    const float* __restrict__ feats,
    const int*   __restrict__ tplts,
    float*       __restrict__ out,
    int n_trip)
{
    const int lane = threadIdx.x & 63;
    const int gl   = threadIdx.x & 3;
    const int groups_per_block = blockDim.x >> 2;
    const int g_global = blockIdx.x * groups_per_block + (threadIdx.x >> 2);
    const int g_stride = gridDim.x * groups_per_block;

    const int* __restrict__ A  = tplts;
    const int* __restrict__ P  = tplts + n_trip;
    const int* __restrict__ Ng = tplts + 2 * n_trip;

    float local = 0.0f;
    for (int t = g_global; t < n_trip; t += g_stride) {
        const float4* ra = (const float4*)(feats + (size_t)A[t]  * N_FEAT);
        const float4* rp = (const float4*)(feats + (size_t)P[t]  * N_FEAT);
        const float4* rn = (const float4*)(feats + (size_t)Ng[t] * N_FEAT);
        float s_ap = 0, s_an = 0, s_aa = 0, s_pp = 0, s_nn = 0;
        #pragma unroll
        for (int c = 0; c < 4; ++c) {
            const float4 a = ra[c*4+gl], p = rp[c*4+gl], q = rn[c*4+gl];
            s_ap += a.x*p.x + a.y*p.y + a.z*p.z + a.w*p.w;
            s_an += a.x*q.x + a.y*q.y + a.z*q.z + a.w*q.w;
            s_aa += a.x*a.x + a.y*a.y + a.z*a.z + a.w*a.w;
            s_pp += p.x*p.x + p.y*p.y + p.z*p.z + p.w*p.w;
            s_nn += q.x*q.x + q.y*q.y + q.z*q.z + q.w*q.w;
        }
        #pragma unroll
        for (int m = 1; m < 4; m <<= 1) {
            s_ap += __shfl_xor(s_ap, m, 64);
            s_an += __shfl_xor(s_an, m, 64);
            s_aa += __shfl_xor(s_aa, m, 64);
            s_pp += __shfl_xor(s_pp, m, 64);
            s_nn += __shfl_xor(s_nn, m, 64);
        }
        if (gl == 0) {
            const float na = fmaxf(sqrtf(s_aa), LSM_EPS);
            const float np = fmaxf(sqrtf(s_pp), LSM_EPS);
            const float nn = fmaxf(sqrtf(s_nn), LSM_EPS);
            local += softplus_f(-(s_ap/(na*np) - LSM_K) * LSM_INV_T)
                   + softplus_f( (s_an/(na*nn) - LSM_K) * LSM_INV_T);
        }
    }
    float v = local;
    #pragma unroll
    for (int m = 4; m < 64; m <<= 1) v += __shfl_xor(v, m, 64);
    __shared__ float wave_sums[4];
    if (lane == 0) wave_sums[threadIdx.x >> 6] = v;
    __syncthreads();
    if (threadIdx.x == 0) {
        float s = wave_sums[0] + wave_sums[1] + wave_sums[2] + wave_sums[3];
        atomicAdd(out, s * (1.0f / (float)n_trip));
    }
}

extern "C" void kernel_launch(void* const* d_in, const int* in_sizes, int n_in,
                              void* d_out, int out_size, void* d_ws, size_t ws_size,
                              hipStream_t stream) {
    const float* feats = (const float*)d_in[0];
    const int*   tplts = (const int*)d_in[1];
    float*       out   = (float*)d_out;
    const int n_trip = in_sizes[1] / 3;
    const int n_rows = in_sizes[0] / N_FEAT;

    const size_t needed = (size_t)n_rows * N_FEAT;  // 1 B per element
    if (ws_size >= needed && (n_trip & 3) == 0) {
        unsigned int* nfeats = (unsigned int*)d_ws;
        // Phase 1 (DIAGNOSTIC x2 sweep this round): normalize -> fp8 table.
        normalize_fp8_kernel<<<dim3(4096), dim3(256), 0, stream>>>(
            feats, nfeats, out, n_rows);
        // Phase 2 (unchanged): batched gather + dot + softplus + mean.
        lsm_loss_fp8_kernel<<<dim3(2048), dim3(256), 0, stream>>>(
            (const uint4*)nfeats, tplts, out, n_trip);
    } else {
        (void)hipMemsetAsync(out, 0, sizeof(float), stream);
        lsm_loss_f32_kernel<<<dim3(2048), dim3(256), 0, stream>>>(
            feats, tplts, out, n_trip);
    }
}

// Round 10
// 235.564 us; speedup vs baseline: 1.0954x; 1.0954x over previous
//
#include <hip/hip_runtime.h>
#include <math.h>

// LSMLoss: triplet cosine margin loss.
//   loss = mean_e[ softplus(-(cos(a,p)-K)/T) + softplus((cos(a,n)-K)/T) ]
// K=0.5, T=0.1, eps=1e-8 (torch CosineSimilarity norm clamp).
// feats: [500000, 64] fp32; tplts: [3, N] int32 (anchor/pos/neg row ids).
//
// R10 = R8 restored (R9's diagnostic x2 sweep removed). Final structure:
//   Phase 1 (~22-30 us, streaming floor): normalize rows in fp32, scale by
//     32, pack to OCP fp8 e4m3 (v_cvt_pk_fp8_f32) -> row = 64 B = ONE cache
//     line. Nontemporal feats loads (read-once; keep L3 for the table).
//     2 rows per 16-lane group per iteration, grid-stride 4096 blocks.
//   Phase 2 (~50-70 us, at the measured ~4.2 TB/s L3 random-line service
//     ceiling): 4-lane groups x 4 triplets per iteration = 12 independent
//     single-line gathers in flight; fp8 decode via v_cvt_pk_f32_fp8;
//     packed-f32 dot; group butterfly; softplus; hierarchical mean with
//     one atomic per block.
// Evidence trail: R3->R4 bytes-invariant, R4->R5 MLP-invariant, R6 diag
// (full sweep, 1/4 waves, warm: 49.3 us), R9 diag (marginal p1 sweep:
// 21.9 us). Both phases are at their structural floors; the rest of
// dur_us is harness reset (512 MB ws re-poison + 128 MB feats restore).

#define LSM_K 0.5f
#define LSM_INV_T 10.0f
#define LSM_EPS 1e-8f
#define N_FEAT 64
#define FP8_SCALE 32.0f
#define FP8_INV_SCALE2 (1.0f / (FP8_SCALE * FP8_SCALE))

typedef float f32x2 __attribute__((ext_vector_type(2)));
typedef float f32x4 __attribute__((ext_vector_type(4)));

__device__ __forceinline__ float softplus_f(float x) {
    // matches jax.nn.softplus: max(x,0) + log1p(exp(-|x|))
    return fmaxf(x, 0.0f) + log1pf(expf(-fabsf(x)));
}

// ---------------- Phase 1: fp32 -> normalized fp8 table (+ zero out) ----
// 16 lanes per row; 2 consecutive rows per group per iteration for ILP.
__global__ __launch_bounds__(256) void normalize_fp8_kernel(
    const float*  __restrict__ feats,
    unsigned int* __restrict__ nfeats,
    float*        __restrict__ out,
    int n_rows)
{
    if (blockIdx.x == 0 && threadIdx.x == 0) *out = 0.0f;  // runs before phase 2

    const int gl = threadIdx.x & 15;
    const int g  = (int)((blockIdx.x * blockDim.x + threadIdx.x) >> 4);
    const int ng = (int)((gridDim.x * blockDim.x) >> 4);
    const int n_pair = n_rows >> 1;

    for (int pr = g; pr < n_pair; pr += ng) {
        const int r0 = pr << 1;
        const f32x4 v0 = __builtin_nontemporal_load(
            (const f32x4*)(feats + (size_t)r0 * N_FEAT) + gl);
        const f32x4 v1 = __builtin_nontemporal_load(
            (const f32x4*)(feats + (size_t)(r0 + 1) * N_FEAT) + gl);

        float s0 = v0.x*v0.x + v0.y*v0.y + v0.z*v0.z + v0.w*v0.w;
        float s1 = v1.x*v1.x + v1.y*v1.y + v1.z*v1.z + v1.w*v1.w;
        #pragma unroll
        for (int m = 1; m < 16; m <<= 1) {
            s0 += __shfl_xor(s0, m, 64);
            s1 += __shfl_xor(s1, m, 64);
        }
        const float sc0 = FP8_SCALE / fmaxf(sqrtf(s0), LSM_EPS);
        const float sc1 = FP8_SCALE / fmaxf(sqrtf(s1), LSM_EPS);

        int pk0 = __builtin_amdgcn_cvt_pk_fp8_f32(v0.x * sc0, v0.y * sc0, 0, false);
        pk0     = __builtin_amdgcn_cvt_pk_fp8_f32(v0.z * sc0, v0.w * sc0, pk0, true);
        int pk1 = __builtin_amdgcn_cvt_pk_fp8_f32(v1.x * sc1, v1.y * sc1, 0, false);
        pk1     = __builtin_amdgcn_cvt_pk_fp8_f32(v1.z * sc1, v1.w * sc1, pk1, true);

        nfeats[(size_t)r0 * 16 + gl]       = (unsigned int)pk0;
        nfeats[(size_t)(r0 + 1) * 16 + gl] = (unsigned int)pk1;
    }

    // tail row if n_rows is odd (not the case at 500k, but stay correct)
    if ((n_rows & 1) && g == 0) {
        const int r = n_rows - 1;
        const f32x4 v = *((const f32x4*)(feats + (size_t)r * N_FEAT) + gl);
        float s = v.x*v.x + v.y*v.y + v.z*v.z + v.w*v.w;
        #pragma unroll
        for (int m = 1; m < 16; m <<= 1)
            s += __shfl_xor(s, m, 64);
        const float sc = FP8_SCALE / fmaxf(sqrtf(s), LSM_EPS);
        int pk = __builtin_amdgcn_cvt_pk_fp8_f32(v.x * sc, v.y * sc, 0, false);
        pk     = __builtin_amdgcn_cvt_pk_fp8_f32(v.z * sc, v.w * sc, pk, true);
        nfeats[(size_t)r * 16 + gl] = (unsigned int)pk;
    }
}

// lane-partial dots of one triplet's 16 B chunks: returns {s_ap, s_an}
__device__ __forceinline__ f32x2 dots3_fp8(const uint4 a, const uint4 p, const uint4 q) {
    const unsigned int aw[4] = {a.x, a.y, a.z, a.w};
    const unsigned int pw[4] = {p.x, p.y, p.z, p.w};
    const unsigned int qw[4] = {q.x, q.y, q.z, q.w};
    f32x2 accp = {0.0f, 0.0f};
    f32x2 accn = {0.0f, 0.0f};
    #pragma unroll
    for (int d = 0; d < 4; ++d) {
        const f32x2 alo = __builtin_amdgcn_cvt_pk_f32_fp8(aw[d], false);
        const f32x2 ahi = __builtin_amdgcn_cvt_pk_f32_fp8(aw[d], true);
        const f32x2 plo = __builtin_amdgcn_cvt_pk_f32_fp8(pw[d], false);
        const f32x2 phi = __builtin_amdgcn_cvt_pk_f32_fp8(pw[d], true);
        const f32x2 qlo = __builtin_amdgcn_cvt_pk_f32_fp8(qw[d], false);
        const f32x2 qhi = __builtin_amdgcn_cvt_pk_f32_fp8(qw[d], true);
        accp += alo * plo;   // v_pk_fma_f32
        accp += ahi * phi;
        accn += alo * qlo;
        accn += ahi * qhi;
    }
    f32x2 r;
    r.x = (accp.x + accp.y) * FP8_INV_SCALE2;
    r.y = (accn.x + accn.y) * FP8_INV_SCALE2;
    return r;
}

// ---------------- Phase 2: batched gather (4 triplets/group/iter) -------
// fp8 row = 64 B = one uint4 per lane of a 4-lane group; 12 independent
// line-gathers in flight per group-iteration.
__global__ __launch_bounds__(256) void lsm_loss_fp8_kernel(
    const uint4* __restrict__ nfeats4,   // 4 x uint4 per row
    const int*   __restrict__ tplts,
    float*       __restrict__ out,
    int n_trip)                           // must be % 4 == 0 (launcher guards)
{
    const int lane = threadIdx.x & 63;
    const int gl   = threadIdx.x & 3;
    const int g        = (int)((blockIdx.x * blockDim.x + threadIdx.x) >> 2);
    const int n_groups = (int)((gridDim.x * blockDim.x) >> 2);

    const int* __restrict__ A  = tplts;
    const int* __restrict__ P  = tplts + n_trip;
    const int* __restrict__ Ng = tplts + 2 * n_trip;

    float local = 0.0f;
    const int n_batch = n_trip >> 2;

    for (int b = g; b < n_batch; b += n_groups) {
        const int t0 = b << 2;
        const int4 ia = *(const int4*)(A  + t0);
        const int4 ip = *(const int4*)(P  + t0);
        const int4 iq = *(const int4*)(Ng + t0);

        const uint4 a0 = nfeats4[(size_t)ia.x * 4 + gl];
        const uint4 a1 = nfeats4[(size_t)ia.y * 4 + gl];
        const uint4 a2 = nfeats4[(size_t)ia.z * 4 + gl];
        const uint4 a3 = nfeats4[(size_t)ia.w * 4 + gl];
        const uint4 p0 = nfeats4[(size_t)ip.x * 4 + gl];
        const uint4 p1 = nfeats4[(size_t)ip.y * 4 + gl];
        const uint4 p2 = nfeats4[(size_t)ip.z * 4 + gl];
        const uint4 p3 = nfeats4[(size_t)ip.w * 4 + gl];
        const uint4 q0 = nfeats4[(size_t)iq.x * 4 + gl];
        const uint4 q1 = nfeats4[(size_t)iq.y * 4 + gl];
        const uint4 q2 = nfeats4[(size_t)iq.z * 4 + gl];
        const uint4 q3 = nfeats4[(size_t)iq.w * 4 + gl];

        f32x2 s0 = dots3_fp8(a0, p0, q0);
        f32x2 s1 = dots3_fp8(a1, p1, q1);
        f32x2 s2 = dots3_fp8(a2, p2, q2);
        f32x2 s3 = dots3_fp8(a3, p3, q3);

        #pragma unroll
        for (int m = 1; m < 4; m <<= 1) {
            s0.x += __shfl_xor(s0.x, m, 64);  s0.y += __shfl_xor(s0.y, m, 64);
            s1.x += __shfl_xor(s1.x, m, 64);  s1.y += __shfl_xor(s1.y, m, 64);
            s2.x += __shfl_xor(s2.x, m, 64);  s2.y += __shfl_xor(s2.y, m, 64);
            s3.x += __shfl_xor(s3.x, m, 64);  s3.y += __shfl_xor(s3.y, m, 64);
        }

        float my_ap = s0.x, my_an = s0.y;
        if (gl == 1) { my_ap = s1.x; my_an = s1.y; }
        if (gl == 2) { my_ap = s2.x; my_an = s2.y; }
        if (gl == 3) { my_ap = s3.x; my_an = s3.y; }

        local += softplus_f(-(my_ap - LSM_K) * LSM_INV_T)
               + softplus_f( (my_an - LSM_K) * LSM_INV_T);
    }

    float v = local;
    #pragma unroll
    for (int m = 1; m < 64; m <<= 1)
        v += __shfl_xor(v, m, 64);

    __shared__ float wave_sums[4];
    const int wave_id = threadIdx.x >> 6;
    if (lane == 0) wave_sums[wave_id] = v;
    __syncthreads();

    if (threadIdx.x == 0) {
        float s = wave_sums[0] + wave_sums[1] + wave_sums[2] + wave_sums[3];
        atomicAdd(out, s * (1.0f / (float)n_trip));
    }
}

// ---------------- Fallback (R2, fp32 direct) ----------------------------
__global__ __launch_bounds__(256) void lsm_loss_f32_kernel(
    const float* __restrict__ feats,
    const int*   __restrict__ tplts,
    float*       __restrict__ out,
    int n_trip)
{
    const int lane = threadIdx.x & 63;
    const int gl   = threadIdx.x & 3;
    const int groups_per_block = blockDim.x >> 2;
    const int g_global = blockIdx.x * groups_per_block + (threadIdx.x >> 2);
    const int g_stride = gridDim.x * groups_per_block;

    const int* __restrict__ A  = tplts;
    const int* __restrict__ P  = tplts + n_trip;
    const int* __restrict__ Ng = tplts + 2 * n_trip;

    float local = 0.0f;
    for (int t = g_global; t < n_trip; t += g_stride) {
        const float4* ra = (const float4*)(feats + (size_t)A[t]  * N_FEAT);
        const float4* rp = (const float4*)(feats + (size_t)P[t]  * N_FEAT);
        const float4* rn = (const float4*)(feats + (size_t)Ng[t] * N_FEAT);
        float s_ap = 0, s_an = 0, s_aa = 0, s_pp = 0, s_nn = 0;
        #pragma unroll
        for (int c = 0; c < 4; ++c) {
            const float4 a = ra[c*4+gl], p = rp[c*4+gl], q = rn[c*4+gl];
            s_ap += a.x*p.x + a.y*p.y + a.z*p.z + a.w*p.w;
            s_an += a.x*q.x + a.y*q.y + a.z*q.z + a.w*q.w;
            s_aa += a.x*a.x + a.y*a.y + a.z*a.z + a.w*a.w;
            s_pp += p.x*p.x + p.y*p.y + p.z*p.z + p.w*p.w;
            s_nn += q.x*q.x + q.y*q.y + q.z*q.z + q.w*q.w;
        }
        #pragma unroll
        for (int m = 1; m < 4; m <<= 1) {
            s_ap += __shfl_xor(s_ap, m, 64);
            s_an += __shfl_xor(s_an, m, 64);
            s_aa += __shfl_xor(s_aa, m, 64);
            s_pp += __shfl_xor(s_pp, m, 64);
            s_nn += __shfl_xor(s_nn, m, 64);
        }
        if (gl == 0) {
            const float na = fmaxf(sqrtf(s_aa), LSM_EPS);
            const float np = fmaxf(sqrtf(s_pp), LSM_EPS);
            const float nn = fmaxf(sqrtf(s_nn), LSM_EPS);
            local += softplus_f(-(s_ap/(na*np) - LSM_K) * LSM_INV_T)
                   + softplus_f( (s_an/(na*nn) - LSM_K) * LSM_INV_T);
        }
    }
    float v = local;
    #pragma unroll
    for (int m = 4; m < 64; m <<= 1) v += __shfl_xor(v, m, 64);
    __shared__ float wave_sums[4];
    if (lane == 0) wave_sums[threadIdx.x >> 6] = v;
    __syncthreads();
    if (threadIdx.x == 0) {
        float s = wave_sums[0] + wave_sums[1] + wave_sums[2] + wave_sums[3];
        atomicAdd(out, s * (1.0f / (float)n_trip));
    }
}

extern "C" void kernel_launch(void* const* d_in, const int* in_sizes, int n_in,
                              void* d_out, int out_size, void* d_ws, size_t ws_size,
                              hipStream_t stream) {
    const float* feats = (const float*)d_in[0];
    const int*   tplts = (const int*)d_in[1];
    float*       out   = (float*)d_out;
    const int n_trip = in_sizes[1] / 3;
    const int n_rows = in_sizes[0] / N_FEAT;

    const size_t needed = (size_t)n_rows * N_FEAT;  // 1 B per element
    if (ws_size >= needed && (n_trip & 3) == 0) {
        unsigned int* nfeats = (unsigned int*)d_ws;
        // Phase 1: normalize -> fp8 table; zeroes *out. 4096 blocks
        // grid-stride, 2 rows per 16-lane group per iteration.
        normalize_fp8_kernel<<<dim3(4096), dim3(256), 0, stream>>>(
            feats, nfeats, out, n_rows);
        // Phase 2: batched gather + dot + softplus + mean.
        lsm_loss_fp8_kernel<<<dim3(2048), dim3(256), 0, stream>>>(
            (const uint4*)nfeats, tplts, out, n_trip);
    } else {
        (void)hipMemsetAsync(out, 0, sizeof(float), stream);
        lsm_loss_f32_kernel<<<dim3(2048), dim3(256), 0, stream>>>(
            feats, tplts, out, n_trip);
    }
}